// Round 1
// 1518.139 us; speedup vs baseline: 1.0836x; 1.0836x over previous
//
#include <hip/hip_runtime.h>
#include <hip/hip_bf16.h>
#include <hip/hip_fp16.h>
#include <cstddef>

// GCN-LSTM decoder, N=50000, E=600000, H=O=128, S=8.
// GCN(feat,W,b) = (A_norm@feat)@W + b  (aggregate first, then GEMM).
// combined=[x,h] => A@combined = [A@x, A@h]; A@x precomputed once.
// GEMMs in bf16 MFMA (16x16x32), computed TRANSPOSED: C'[p][node], where for
// the cell GEMM p = jcol*4 + gate so one lane's 4 acc regs = the 4 LSTM gates
// of one (node, jcol) -> fused epilogue with no cross-lane traffic.
// Gather sources kept in fp16 (halves random-gather bytes vs fp32; adds only
// 2^-11 rel rounding, below the bf16 (2^-8) GEMM-input quantization).

#define TPB 256

typedef __attribute__((ext_vector_type(8))) short bf16x8;   // 8 bf16 = 4 VGPR
typedef __attribute__((ext_vector_type(4))) float f32x4;

__device__ __forceinline__ float sigf(float x) {
    return 1.0f / (1.0f + __expf(-x));
}
__device__ __forceinline__ float tanhfast(float x) {
    return 1.0f - 2.0f / (__expf(2.0f * x) + 1.0f);
}

// ---------------- CSR build ----------------

__global__ void k_hist(const int* __restrict__ dst, int* __restrict__ counts, int E) {
    int e = blockIdx.x * TPB + threadIdx.x;
    if (e < E) atomicAdd(&counts[dst[e]], 1);
}

__global__ void k_scan_block(const int* __restrict__ counts, int* __restrict__ offsets,
                             int* __restrict__ sums, int N) {
    __shared__ int s[TPB];
    int tid = threadIdx.x;
    int gid = blockIdx.x * TPB + tid;
    int v = (gid < N) ? counts[gid] : 0;
    s[tid] = v;
    __syncthreads();
    for (int d = 1; d < TPB; d <<= 1) {
        int t = (tid >= d) ? s[tid - d] : 0;
        __syncthreads();
        s[tid] += t;
        __syncthreads();
    }
    if (gid < N) offsets[gid] = s[tid] - v;
    if (tid == TPB - 1) sums[blockIdx.x] = s[tid];
}

__global__ void k_scan_tops(int* __restrict__ sums, int nb) {
    __shared__ int s[TPB];
    int tid = threadIdx.x;
    int v = (tid < nb) ? sums[tid] : 0;
    s[tid] = v;
    __syncthreads();
    for (int d = 1; d < TPB; d <<= 1) {
        int t = (tid >= d) ? s[tid - d] : 0;
        __syncthreads();
        s[tid] += t;
        __syncthreads();
    }
    if (tid < nb) sums[tid] = s[tid] - v;
}

__global__ void k_scan_finish(const int* __restrict__ counts, int* __restrict__ offsets,
                              const int* __restrict__ sums, int* __restrict__ cursor,
                              float* __restrict__ dinv, int N, int E) {
    int gid = blockIdx.x * TPB + threadIdx.x;
    if (gid < N) {
        int off = offsets[gid] + sums[blockIdx.x];
        offsets[gid] = off;
        cursor[gid]  = off;
        dinv[gid]    = rsqrtf((float)(counts[gid] + 1));
    }
    if (gid == 0) offsets[N] = E;
}

__global__ void k_csr_scatter(const int* __restrict__ src, const int* __restrict__ dst,
                              const float* __restrict__ dinv, int* __restrict__ cursor,
                              int* __restrict__ csr_src, float* __restrict__ csr_w, int E) {
    int e = blockIdx.x * TPB + threadIdx.x;
    if (e >= E) return;
    int d = dst[e], s = src[e];
    int pos = atomicAdd(&cursor[d], 1);
    csr_src[pos] = s;
    csr_w[pos] = dinv[s] * dinv[d];
}

// ---------------- fp32 -> fp16 convert ----------------

__global__ void k_f32tof16(const float* __restrict__ in, __half* __restrict__ out, int n4) {
    int i = blockIdx.x * TPB + threadIdx.x;    // 4 floats per thread
    if (i >= n4) return;
    float4 v = ((const float4*)in)[i];
    __half2 lo = __floats2half2_rn(v.x, v.y);
    __half2 hi = __floats2half2_rn(v.z, v.w);
    ((__half2*)out)[2 * i]     = lo;
    ((__half2*)out)[2 * i + 1] = hi;
}

// ---------------- aggregation: agg(bf16) = A_norm @ feat(fp16) ----------------
// One wave per node; lane holds 2 channels (fp16x2 = 4B/lane, 256B/edge/wave).

__global__ __launch_bounds__(TPB) void k_aggregate_h(
        const __half* __restrict__ feat, __hip_bfloat16* __restrict__ agg,
        const int* __restrict__ offsets, const int* __restrict__ csr_src,
        const float* __restrict__ csr_w, const float* __restrict__ dinv, int N) {
    int node = blockIdx.x * 4 + (threadIdx.x >> 6);
    if (node >= N) return;
    int lane = threadIdx.x & 63;
    const __half2* f2 = (const __half2*)feat;
    float2 self = __half22float2(f2[(size_t)node * 64 + lane]);
    float di = dinv[node];
    float w0 = di * di;
    float accx = w0 * self.x, accy = w0 * self.y;
    int b = offsets[node], e = offsets[node + 1];
    int k = b;
    for (; k + 1 < e; k += 2) {
        int s0 = csr_src[k], s1 = csr_src[k + 1];
        float wa = csr_w[k], wb = csr_w[k + 1];
        float2 v0 = __half22float2(f2[(size_t)s0 * 64 + lane]);
        float2 v1 = __half22float2(f2[(size_t)s1 * 64 + lane]);
        accx = fmaf(wa, v0.x, accx);
        accy = fmaf(wa, v0.y, accy);
        accx = fmaf(wb, v1.x, accx);
        accy = fmaf(wb, v1.y, accy);
    }
    if (k < e) {
        int s = csr_src[k];
        float w = csr_w[k];
        float2 v = __half22float2(f2[(size_t)s * 64 + lane]);
        accx = fmaf(w, v.x, accx);
        accy = fmaf(w, v.y, accy);
    }
    __hip_bfloat162 r;
    r.x = __float2bfloat16(accx);
    r.y = __float2bfloat16(accy);
    ((__hip_bfloat162*)agg)[(size_t)node * 64 + lane] = r;
}

// dual-source aggregate (x and c share the CSR stream; 2 gathers in flight)
__global__ __launch_bounds__(TPB) void k_aggregate_h2(
        const __half* __restrict__ fa, const __half* __restrict__ fb,
        __hip_bfloat16* __restrict__ aggA, __hip_bfloat16* __restrict__ aggB,
        const int* __restrict__ offsets, const int* __restrict__ csr_src,
        const float* __restrict__ csr_w, const float* __restrict__ dinv, int N) {
    int node = blockIdx.x * 4 + (threadIdx.x >> 6);
    if (node >= N) return;
    int lane = threadIdx.x & 63;
    const __half2* fa2 = (const __half2*)fa;
    const __half2* fb2 = (const __half2*)fb;
    size_t selfIdx = (size_t)node * 64 + lane;
    float di = dinv[node];
    float w0 = di * di;
    float2 sa = __half22float2(fa2[selfIdx]);
    float2 sb = __half22float2(fb2[selfIdx]);
    float ax = w0 * sa.x, ay = w0 * sa.y;
    float bx = w0 * sb.x, by = w0 * sb.y;
    int b = offsets[node], e = offsets[node + 1];
    for (int k = b; k < e; ++k) {
        int s = csr_src[k];
        float w = csr_w[k];
        size_t si = (size_t)s * 64 + lane;
        float2 va = __half22float2(fa2[si]);
        float2 vb = __half22float2(fb2[si]);
        ax = fmaf(w, va.x, ax);
        ay = fmaf(w, va.y, ay);
        bx = fmaf(w, vb.x, bx);
        by = fmaf(w, vb.y, by);
    }
    __hip_bfloat162 ra, rb;
    ra.x = __float2bfloat16(ax); ra.y = __float2bfloat16(ay);
    rb.x = __float2bfloat16(bx); rb.y = __float2bfloat16(by);
    ((__hip_bfloat162*)aggA)[selfIdx] = ra;
    ((__hip_bfloat162*)aggB)[selfIdx] = rb;
}

// ---------------- weight packing into MFMA A-frag order ----------------
// Layout: Wp[ks][pblk][lane][j] = W'[pblk*16 + (lane&15)][ks*32 + (lane>>4)*8 + j]

__global__ void k_pack_w128(const float* __restrict__ W, __hip_bfloat16* __restrict__ Wp) {
    int idx = blockIdx.x * TPB + threadIdx.x;     // 4*8*64*8 = 16384
    if (idx >= 16384) return;
    int j = idx & 7, lane = (idx >> 3) & 63, pblk = (idx >> 9) & 7, ks = idx >> 12;
    int k = ks * 32 + (lane >> 4) * 8 + j;
    int col = pblk * 16 + (lane & 15);
    Wp[idx] = __float2bfloat16(W[k * 128 + col]);
}

// cell weights: p = jcol*4 + gate  (gate order f,i,o,g matches bcell blocks)
__global__ void k_pack_wcell(const float* __restrict__ W, __hip_bfloat16* __restrict__ Wp, int S) {
    int idx = blockIdx.x * TPB + threadIdx.x;     // S * 8*32*64*8 = S*131072
    if (idx >= S * 131072) return;
    int j = idx & 7, lane = (idx >> 3) & 63, pblk = (idx >> 9) & 31;
    int ks = (idx >> 14) & 7, s = idx >> 17;
    int p = pblk * 16 + (lane & 15);
    int jcol = p >> 2, gate = p & 3;
    int k = ks * 32 + (lane >> 4) * 8 + j;
    Wp[idx] = __float2bfloat16(W[(size_t)s * 131072 + k * 512 + gate * 128 + jcol]);
}

// ---------------- transposed MFMA GEMM: C[node][128] = agg @ W + b ----------------
// M = 128 weight cols (p), N-dim = nodes. Block: 128p x 128nodes, 4 waves 2x2.
// Cout (fp32) and outh (fp16) independently nullable.

__global__ __launch_bounds__(TPB) void k_gemm_t(
        const __hip_bfloat16* __restrict__ Ap,     // packed [4][8][64][8]
        const __hip_bfloat16* __restrict__ featb,  // [N][128] bf16
        const float* __restrict__ bias, float* __restrict__ Cout,
        __half* __restrict__ outh, int N) {
    __shared__ __align__(16) short Bs[128 * 40];   // 128 nodes x 32 bf16, stride 40
    int tid = threadIdx.x;
    int wave = tid >> 6, lane = tid & 63;
    int w_p = wave >> 1, w_n = wave & 1;
    int n0 = blockIdx.x * 128;
    int quad = lane >> 4, m16 = lane & 15;
    f32x4 zero = {0.f, 0.f, 0.f, 0.f};
    f32x4 acc[4][4];
    #pragma unroll
    for (int t = 0; t < 4; ++t)
        #pragma unroll
        for (int g = 0; g < 4; ++g) acc[t][g] = zero;

    for (int ks = 0; ks < 4; ++ks) {
        int kbase = ks * 32;
        __syncthreads();
        #pragma unroll
        for (int it = 0; it < 2; ++it) {
            int lin = it * TPB + tid;
            int row = lin >> 2, seg = lin & 3;
            int node = n0 + row;
            f32x4 v = zero;
            if (node < N) v = *(const f32x4*)(featb + (size_t)node * 128 + kbase + seg * 8);
            *(f32x4*)&Bs[row * 40 + seg * 8] = v;
        }
        __syncthreads();
        bf16x8 a[4], b[4];
        #pragma unroll
        for (int t = 0; t < 4; ++t)
            a[t] = *(const bf16x8*)(Ap + (((size_t)ks * 8 + w_p * 4 + t) * 64 + lane) * 8);
        #pragma unroll
        for (int g = 0; g < 4; ++g)
            b[g] = *(const bf16x8*)&Bs[(w_n * 64 + g * 16 + m16) * 40 + quad * 8];
        #pragma unroll
        for (int t = 0; t < 4; ++t)
            #pragma unroll
            for (int g = 0; g < 4; ++g)
                acc[t][g] = __builtin_amdgcn_mfma_f32_16x16x32_bf16(a[t], b[g], acc[t][g], 0, 0, 0);
    }
    #pragma unroll
    for (int t = 0; t < 4; ++t) {
        int p = w_p * 64 + t * 16 + quad * 4;
        f32x4 bv = *(const f32x4*)(bias + p);
        #pragma unroll
        for (int g = 0; g < 4; ++g) {
            int nd = n0 + w_n * 64 + g * 16 + m16;
            if (nd < N) {
                f32x4 o = acc[t][g] + bv;
                if (Cout) *(f32x4*)(Cout + (size_t)nd * 128 + p) = o;
                if (outh) {
                    __half2 lo = __floats2half2_rn(o.x, o.y);
                    __half2 hi = __floats2half2_rn(o.z, o.w);
                    __half2* hp = (__half2*)(outh + (size_t)nd * 128 + p);
                    hp[0] = lo;
                    hp[1] = hi;
                }
            }
        }
    }
}

// ---------------- fused cell GEMM + LSTM gates (transposed, gate-packed) ----------------
// C'[p][node], p = jcol*4+gate, K=256 (ax | ah). Lane reg r = gate r of jcol.

__global__ __launch_bounds__(TPB) void k_cell_t(
        const __hip_bfloat16* __restrict__ Ap,     // packed [8][32][64][8] for this step
        const __hip_bfloat16* __restrict__ axb, const __hip_bfloat16* __restrict__ ahb,
        const float* __restrict__ bias,            // bcell + s*512
        float* __restrict__ cbuf, float* __restrict__ hout,
        __half* __restrict__ houth,                // fp16 copy of h for next aggregate
        float* __restrict__ hfin, int N) {
    __shared__ __align__(16) short Bs[128 * 40];
    int tid = threadIdx.x;
    int wave = tid >> 6, lane = tid & 63;
    int w_p = wave >> 1, w_n = wave & 1;
    int n0 = blockIdx.x * 128;
    int p0 = blockIdx.y * 128;
    int quad = lane >> 4, m16 = lane & 15;
    f32x4 zero = {0.f, 0.f, 0.f, 0.f};
    f32x4 acc[4][4];
    #pragma unroll
    for (int t = 0; t < 4; ++t)
        #pragma unroll
        for (int g = 0; g < 4; ++g) acc[t][g] = zero;

    for (int ks = 0; ks < 8; ++ks) {
        const __hip_bfloat16* fsrc = (ks < 4) ? axb : ahb;
        int kbase = (ks & 3) * 32;
        __syncthreads();
        #pragma unroll
        for (int it = 0; it < 2; ++it) {
            int lin = it * TPB + tid;
            int row = lin >> 2, seg = lin & 3;
            int node = n0 + row;
            f32x4 v = zero;
            if (node < N) v = *(const f32x4*)(fsrc + (size_t)node * 128 + kbase + seg * 8);
            *(f32x4*)&Bs[row * 40 + seg * 8] = v;
        }
        __syncthreads();
        bf16x8 a[4], b[4];
        #pragma unroll
        for (int t = 0; t < 4; ++t)
            a[t] = *(const bf16x8*)(Ap + (((size_t)ks * 32 + (p0 >> 4) + w_p * 4 + t) * 64 + lane) * 8);
        #pragma unroll
        for (int g = 0; g < 4; ++g)
            b[g] = *(const bf16x8*)&Bs[(w_n * 64 + g * 16 + m16) * 40 + quad * 8];
        #pragma unroll
        for (int t = 0; t < 4; ++t)
            #pragma unroll
            for (int g = 0; g < 4; ++g)
                acc[t][g] = __builtin_amdgcn_mfma_f32_16x16x32_bf16(a[t], b[g], acc[t][g], 0, 0, 0);
    }
    #pragma unroll
    for (int t = 0; t < 4; ++t) {
        int p = p0 + w_p * 64 + t * 16 + quad * 4;
        int jcol = p >> 2;
        float bf = bias[jcol], bi = bias[128 + jcol], bo = bias[256 + jcol], bg = bias[384 + jcol];
        #pragma unroll
        for (int g = 0; g < 4; ++g) {
            int nd = n0 + w_n * 64 + g * 16 + m16;
            if (nd < N) {
                float fv = sigf(acc[t][g].x + bf);
                float iv = sigf(acc[t][g].y + bi);
                float ov = sigf(acc[t][g].z + bo);
                float gv = tanhfast(acc[t][g].w + bg);
                size_t idx = (size_t)nd * 128 + jcol;
                float cp = cbuf[idx];
                float cn = fmaf(fv, cp, iv * gv);
                cbuf[idx] = cn;
                float hn = ov * tanhfast(cn);
                hout[idx] = hn;
                houth[idx] = __float2half(hn);
                if (hfin) hfin[idx] = hn;
            }
        }
    }
}

// ---------------- launch ----------------

extern "C" void kernel_launch(void* const* d_in, const int* in_sizes, int n_in,
                              void* d_out, int out_size, void* d_ws, size_t ws_size,
                              hipStream_t stream) {
    const float* x  = (const float*)d_in[0];
    const float* c  = (const float*)d_in[1];
    const int*   ei = (const int*)d_in[2];
    const float* Wh = (const float*)d_in[3];
    const float* bh = (const float*)d_in[4];
    const float* Wc = (const float*)d_in[5];
    const float* bc = (const float*)d_in[6];
    const float* Wcell = (const float*)d_in[7];
    const float* bcell = (const float*)d_in[8];
    float* out = (float*)d_out;

    const int N = in_sizes[0] / 128;
    const int E = in_sizes[2] / 2;
    const int S = in_sizes[7] / (256 * 512);
    const int* srcp = ei;
    const int* dstp = ei + E;

    // output layout: hs [S,N,128] | h_fin [N,128] | c_fin [N,128]
    float* hs   = out;
    float* hfin = out + (size_t)S * N * 128;
    float* cbuf = hfin + (size_t)N * 128;

    char* w = (char*)d_ws;
    size_t off = 0;
    auto alloc = [&](size_t bytes) -> void* {
        void* p = w + off;
        off += (bytes + 255) & ~(size_t)255;
        return p;
    };
    int*   counts  = (int*)alloc((size_t)N * 4);
    int*   offsets = (int*)alloc((size_t)(N + 1) * 4);
    int*   cursor  = (int*)alloc((size_t)N * 4);
    int*   sums    = (int*)alloc(256 * 4);
    int*   csr_src = (int*)alloc((size_t)E * 4);
    float* csr_w   = (float*)alloc((size_t)E * 4);
    float* dinv    = (float*)alloc((size_t)N * 4);
    __hip_bfloat16* axb = (__hip_bfloat16*)alloc((size_t)N * 128 * 2);
    __hip_bfloat16* acb = (__hip_bfloat16*)alloc((size_t)N * 128 * 2);  // ac, then ah per step
    __half* xh = (__half*)alloc((size_t)N * 128 * 2);
    __half* ch = (__half*)alloc((size_t)N * 128 * 2);
    __half* hh = (__half*)alloc((size_t)N * 128 * 2);   // fp16 h (h0, then h_s)
    __hip_bfloat16* WhP = (__hip_bfloat16*)alloc(16384 * 2);
    __hip_bfloat16* WcP = (__hip_bfloat16*)alloc(16384 * 2);
    __hip_bfloat16* WcellP = (__hip_bfloat16*)alloc((size_t)S * 131072 * 2);
    (void)ws_size; (void)n_in; (void)out_size;

    hipMemsetAsync(counts, 0, (size_t)N * 4, stream);
    int eblk = (E + TPB - 1) / TPB;
    int nb   = (N + TPB - 1) / TPB;
    k_hist<<<eblk, TPB, 0, stream>>>(dstp, counts, E);
    k_scan_block<<<nb, TPB, 0, stream>>>(counts, offsets, sums, N);
    k_scan_tops<<<1, TPB, 0, stream>>>(sums, nb);
    k_scan_finish<<<nb, TPB, 0, stream>>>(counts, offsets, sums, cursor, dinv, N, E);
    k_csr_scatter<<<eblk, TPB, 0, stream>>>(srcp, dstp, dinv, cursor, csr_src, csr_w, E);

    // pack weights to MFMA frag order (bf16)
    k_pack_w128<<<64, TPB, 0, stream>>>(Wh, WhP);
    k_pack_w128<<<64, TPB, 0, stream>>>(Wc, WcP);
    k_pack_wcell<<<(S * 131072 + TPB - 1) / TPB, TPB, 0, stream>>>(Wcell, WcellP, S);

    // fp16 gather sources for x and c
    int n4 = N * 128 / 4;
    int cb = (n4 + TPB - 1) / TPB;
    k_f32tof16<<<cb, TPB, 0, stream>>>(x, xh, n4);
    k_f32tof16<<<cb, TPB, 0, stream>>>(c, ch, n4);

    int nagg = (N + 3) / 4;
    int ngt  = (N + 127) / 128;
    k_aggregate_h2<<<nagg, TPB, 0, stream>>>(xh, ch, axb, acb, offsets, csr_src, csr_w, dinv, N);
    k_gemm_t<<<ngt, TPB, 0, stream>>>(WhP, axb, bh, nullptr, hh, N);   // h0 only needed as fp16 gather src
    k_gemm_t<<<ngt, TPB, 0, stream>>>(WcP, acb, bc, cbuf, nullptr, N);

    for (int s = 0; s < S; ++s) {
        k_aggregate_h<<<nagg, TPB, 0, stream>>>(hh, acb, offsets, csr_src, csr_w, dinv, N);
        k_cell_t<<<dim3(ngt, 4), TPB, 0, stream>>>(
            WcellP + (size_t)s * 131072, axb, acb, bcell + (size_t)s * 512,
            cbuf, hs + (size_t)s * N * 128, hh, (s == S - 1) ? hfin : nullptr, N);
    }
}

// Round 2
// 1346.337 us; speedup vs baseline: 1.2219x; 1.1276x over previous
//
#include <hip/hip_runtime.h>
#include <hip/hip_bf16.h>
#include <hip/hip_fp16.h>
#include <cstddef>

// GCN-LSTM decoder, N=50000, E=600000, H=O=128, S=8.
// GCN(feat,W,b) = (A_norm@feat)@W + b  (aggregate first, then GEMM).
// combined=[x,h] => A@combined = [A@x, A@h]; A@x precomputed once.
// GEMMs in bf16 MFMA (16x16x32), computed TRANSPOSED: C'[p][node], where for
// the cell GEMM p = jcol*4 + gate so one lane's 4 acc regs = the 4 LSTM gates
// of one (node, jcol) -> fused epilogue with no cross-lane traffic.
// Gather sources kept in fp16. CSR (src,w) fused into one int2 stream and the
// edge loop unrolled 4-deep: 4 gathers in flight (latency-bound fix).
// Cell GEMM: full 256-K B-panel staged ONCE into 80 KB LDS (1 barrier), then
// in-kernel loop over the 4 p-blocks (was grid-y=4 with 16 barriers/block).

#define TPB 256

typedef __attribute__((ext_vector_type(8))) short bf16x8;   // 8 bf16 = 4 VGPR
typedef __attribute__((ext_vector_type(4))) float f32x4;

__device__ __forceinline__ float sigf(float x) {
    return 1.0f / (1.0f + __expf(-x));
}
__device__ __forceinline__ float tanhfast(float x) {
    return 1.0f - 2.0f / (__expf(2.0f * x) + 1.0f);
}

// ---------------- CSR build ----------------

__global__ void k_hist(const int* __restrict__ dst, int* __restrict__ counts, int E) {
    int e = blockIdx.x * TPB + threadIdx.x;
    if (e < E) atomicAdd(&counts[dst[e]], 1);
}

__global__ void k_scan_block(const int* __restrict__ counts, int* __restrict__ offsets,
                             int* __restrict__ sums, int N) {
    __shared__ int s[TPB];
    int tid = threadIdx.x;
    int gid = blockIdx.x * TPB + tid;
    int v = (gid < N) ? counts[gid] : 0;
    s[tid] = v;
    __syncthreads();
    for (int d = 1; d < TPB; d <<= 1) {
        int t = (tid >= d) ? s[tid - d] : 0;
        __syncthreads();
        s[tid] += t;
        __syncthreads();
    }
    if (gid < N) offsets[gid] = s[tid] - v;
    if (tid == TPB - 1) sums[blockIdx.x] = s[tid];
}

__global__ void k_scan_tops(int* __restrict__ sums, int nb) {
    __shared__ int s[TPB];
    int tid = threadIdx.x;
    int v = (tid < nb) ? sums[tid] : 0;
    s[tid] = v;
    __syncthreads();
    for (int d = 1; d < TPB; d <<= 1) {
        int t = (tid >= d) ? s[tid - d] : 0;
        __syncthreads();
        s[tid] += t;
        __syncthreads();
    }
    if (tid < nb) sums[tid] = s[tid] - v;
}

__global__ void k_scan_finish(const int* __restrict__ counts, int* __restrict__ offsets,
                              const int* __restrict__ sums, int* __restrict__ cursor,
                              float* __restrict__ dinv, int N, int E) {
    int gid = blockIdx.x * TPB + threadIdx.x;
    if (gid < N) {
        int off = offsets[gid] + sums[blockIdx.x];
        offsets[gid] = off;
        cursor[gid]  = off;
        dinv[gid]    = rsqrtf((float)(counts[gid] + 1));
    }
    if (gid == 0) offsets[N] = E;
}

__global__ void k_csr_scatter(const int* __restrict__ src, const int* __restrict__ dst,
                              const float* __restrict__ dinv, int* __restrict__ cursor,
                              int2* __restrict__ csr_sw, int E) {
    int e = blockIdx.x * TPB + threadIdx.x;
    if (e >= E) return;
    int d = dst[e], s = src[e];
    int pos = atomicAdd(&cursor[d], 1);
    int2 r;
    r.x = s;
    r.y = __float_as_int(dinv[s] * dinv[d]);
    csr_sw[pos] = r;
}

// ---------------- fp32 -> fp16 convert ----------------

__global__ void k_f32tof16(const float* __restrict__ in, __half* __restrict__ out, int n4) {
    int i = blockIdx.x * TPB + threadIdx.x;    // 4 floats per thread
    if (i >= n4) return;
    float4 v = ((const float4*)in)[i];
    __half2 lo = __floats2half2_rn(v.x, v.y);
    __half2 hi = __floats2half2_rn(v.z, v.w);
    ((__half2*)out)[2 * i]     = lo;
    ((__half2*)out)[2 * i + 1] = hi;
}

// ---------------- aggregation: agg(bf16) = A_norm @ feat(fp16) ----------------
// One wave per node; lane holds 2 channels. Edge loop 4-deep: 4 gathers in flight.

__global__ __launch_bounds__(TPB) void k_aggregate_h(
        const __half* __restrict__ feat, __hip_bfloat16* __restrict__ agg,
        const int* __restrict__ offsets, const int2* __restrict__ sw,
        const float* __restrict__ dinv, int N) {
    int node = blockIdx.x * 4 + (threadIdx.x >> 6);
    if (node >= N) return;
    int lane = threadIdx.x & 63;
    const __half2* f2 = (const __half2*)feat;
    float2 self = __half22float2(f2[(size_t)node * 64 + lane]);
    float di = dinv[node];
    float w0 = di * di;
    float accx = w0 * self.x, accy = w0 * self.y;
    int b = offsets[node], e = offsets[node + 1];
    int k = b;
    for (; k + 3 < e; k += 4) {
        int2 e0 = sw[k], e1 = sw[k + 1], e2 = sw[k + 2], e3 = sw[k + 3];
        float2 v0 = __half22float2(f2[(size_t)e0.x * 64 + lane]);
        float2 v1 = __half22float2(f2[(size_t)e1.x * 64 + lane]);
        float2 v2 = __half22float2(f2[(size_t)e2.x * 64 + lane]);
        float2 v3 = __half22float2(f2[(size_t)e3.x * 64 + lane]);
        float wa = __int_as_float(e0.y), wb = __int_as_float(e1.y);
        float wc = __int_as_float(e2.y), wd = __int_as_float(e3.y);
        accx = fmaf(wa, v0.x, accx); accy = fmaf(wa, v0.y, accy);
        accx = fmaf(wb, v1.x, accx); accy = fmaf(wb, v1.y, accy);
        accx = fmaf(wc, v2.x, accx); accy = fmaf(wc, v2.y, accy);
        accx = fmaf(wd, v3.x, accx); accy = fmaf(wd, v3.y, accy);
    }
    for (; k < e; ++k) {
        int2 e0 = sw[k];
        float2 v = __half22float2(f2[(size_t)e0.x * 64 + lane]);
        float w = __int_as_float(e0.y);
        accx = fmaf(w, v.x, accx);
        accy = fmaf(w, v.y, accy);
    }
    __hip_bfloat162 r;
    r.x = __float2bfloat16(accx);
    r.y = __float2bfloat16(accy);
    ((__hip_bfloat162*)agg)[(size_t)node * 64 + lane] = r;
}

// dual-source aggregate (x and c share the CSR stream; 2x2 gathers in flight)
__global__ __launch_bounds__(TPB) void k_aggregate_h2(
        const __half* __restrict__ fa, const __half* __restrict__ fb,
        __hip_bfloat16* __restrict__ aggA, __hip_bfloat16* __restrict__ aggB,
        const int* __restrict__ offsets, const int2* __restrict__ sw,
        const float* __restrict__ dinv, int N) {
    int node = blockIdx.x * 4 + (threadIdx.x >> 6);
    if (node >= N) return;
    int lane = threadIdx.x & 63;
    const __half2* fa2 = (const __half2*)fa;
    const __half2* fb2 = (const __half2*)fb;
    size_t selfIdx = (size_t)node * 64 + lane;
    float di = dinv[node];
    float w0 = di * di;
    float2 sa = __half22float2(fa2[selfIdx]);
    float2 sb = __half22float2(fb2[selfIdx]);
    float ax = w0 * sa.x, ay = w0 * sa.y;
    float bx = w0 * sb.x, by = w0 * sb.y;
    int b = offsets[node], e = offsets[node + 1];
    int k = b;
    for (; k + 1 < e; k += 2) {
        int2 e0 = sw[k], e1 = sw[k + 1];
        size_t i0 = (size_t)e0.x * 64 + lane;
        size_t i1 = (size_t)e1.x * 64 + lane;
        float2 va0 = __half22float2(fa2[i0]);
        float2 vb0 = __half22float2(fb2[i0]);
        float2 va1 = __half22float2(fa2[i1]);
        float2 vb1 = __half22float2(fb2[i1]);
        float wa = __int_as_float(e0.y), wb = __int_as_float(e1.y);
        ax = fmaf(wa, va0.x, ax); ay = fmaf(wa, va0.y, ay);
        bx = fmaf(wa, vb0.x, bx); by = fmaf(wa, vb0.y, by);
        ax = fmaf(wb, va1.x, ax); ay = fmaf(wb, va1.y, ay);
        bx = fmaf(wb, vb1.x, bx); by = fmaf(wb, vb1.y, by);
    }
    if (k < e) {
        int2 e0 = sw[k];
        size_t i0 = (size_t)e0.x * 64 + lane;
        float2 va = __half22float2(fa2[i0]);
        float2 vb = __half22float2(fb2[i0]);
        float w = __int_as_float(e0.y);
        ax = fmaf(w, va.x, ax); ay = fmaf(w, va.y, ay);
        bx = fmaf(w, vb.x, bx); by = fmaf(w, vb.y, by);
    }
    __hip_bfloat162 ra, rb;
    ra.x = __float2bfloat16(ax); ra.y = __float2bfloat16(ay);
    rb.x = __float2bfloat16(bx); rb.y = __float2bfloat16(by);
    ((__hip_bfloat162*)aggA)[selfIdx] = ra;
    ((__hip_bfloat162*)aggB)[selfIdx] = rb;
}

// ---------------- weight packing into MFMA A-frag order ----------------
// Layout: Wp[ks][pblk][lane][j] = W'[pblk*16 + (lane&15)][ks*32 + (lane>>4)*8 + j]

__global__ void k_pack_w128(const float* __restrict__ W, __hip_bfloat16* __restrict__ Wp) {
    int idx = blockIdx.x * TPB + threadIdx.x;     // 4*8*64*8 = 16384
    if (idx >= 16384) return;
    int j = idx & 7, lane = (idx >> 3) & 63, pblk = (idx >> 9) & 7, ks = idx >> 12;
    int k = ks * 32 + (lane >> 4) * 8 + j;
    int col = pblk * 16 + (lane & 15);
    Wp[idx] = __float2bfloat16(W[k * 128 + col]);
}

// cell weights: p = jcol*4 + gate  (gate order f,i,o,g matches bcell blocks)
__global__ void k_pack_wcell(const float* __restrict__ W, __hip_bfloat16* __restrict__ Wp, int S) {
    int idx = blockIdx.x * TPB + threadIdx.x;     // S * 8*32*64*8 = S*131072
    if (idx >= S * 131072) return;
    int j = idx & 7, lane = (idx >> 3) & 63, pblk = (idx >> 9) & 31;
    int ks = (idx >> 14) & 7, s = idx >> 17;
    int p = pblk * 16 + (lane & 15);
    int jcol = p >> 2, gate = p & 3;
    int k = ks * 32 + (lane >> 4) * 8 + j;
    Wp[idx] = __float2bfloat16(W[(size_t)s * 131072 + k * 512 + gate * 128 + jcol]);
}

// ---------------- transposed MFMA GEMM: C[node][128] = agg @ W + b ----------------
// M = 128 weight cols (p), N-dim = nodes. Block: 128p x 128nodes, 4 waves 2x2.
// Cout (fp32) and outh (fp16) independently nullable.

__global__ __launch_bounds__(TPB) void k_gemm_t(
        const __hip_bfloat16* __restrict__ Ap,     // packed [4][8][64][8]
        const __hip_bfloat16* __restrict__ featb,  // [N][128] bf16
        const float* __restrict__ bias, float* __restrict__ Cout,
        __half* __restrict__ outh, int N) {
    __shared__ __align__(16) short Bs[128 * 40];   // 128 nodes x 32 bf16, stride 40
    int tid = threadIdx.x;
    int wave = tid >> 6, lane = tid & 63;
    int w_p = wave >> 1, w_n = wave & 1;
    int n0 = blockIdx.x * 128;
    int quad = lane >> 4, m16 = lane & 15;
    f32x4 zero = {0.f, 0.f, 0.f, 0.f};
    f32x4 acc[4][4];
    #pragma unroll
    for (int t = 0; t < 4; ++t)
        #pragma unroll
        for (int g = 0; g < 4; ++g) acc[t][g] = zero;

    for (int ks = 0; ks < 4; ++ks) {
        int kbase = ks * 32;
        __syncthreads();
        #pragma unroll
        for (int it = 0; it < 2; ++it) {
            int lin = it * TPB + tid;
            int row = lin >> 2, seg = lin & 3;
            int node = n0 + row;
            f32x4 v = zero;
            if (node < N) v = *(const f32x4*)(featb + (size_t)node * 128 + kbase + seg * 8);
            *(f32x4*)&Bs[row * 40 + seg * 8] = v;
        }
        __syncthreads();
        bf16x8 a[4], b[4];
        #pragma unroll
        for (int t = 0; t < 4; ++t)
            a[t] = *(const bf16x8*)(Ap + (((size_t)ks * 8 + w_p * 4 + t) * 64 + lane) * 8);
        #pragma unroll
        for (int g = 0; g < 4; ++g)
            b[g] = *(const bf16x8*)&Bs[(w_n * 64 + g * 16 + m16) * 40 + quad * 8];
        #pragma unroll
        for (int t = 0; t < 4; ++t)
            #pragma unroll
            for (int g = 0; g < 4; ++g)
                acc[t][g] = __builtin_amdgcn_mfma_f32_16x16x32_bf16(a[t], b[g], acc[t][g], 0, 0, 0);
    }
    #pragma unroll
    for (int t = 0; t < 4; ++t) {
        int p = w_p * 64 + t * 16 + quad * 4;
        f32x4 bv = *(const f32x4*)(bias + p);
        #pragma unroll
        for (int g = 0; g < 4; ++g) {
            int nd = n0 + w_n * 64 + g * 16 + m16;
            if (nd < N) {
                f32x4 o = acc[t][g] + bv;
                if (Cout) *(f32x4*)(Cout + (size_t)nd * 128 + p) = o;
                if (outh) {
                    __half2 lo = __floats2half2_rn(o.x, o.y);
                    __half2 hi = __floats2half2_rn(o.z, o.w);
                    __half2* hp = (__half2*)(outh + (size_t)nd * 128 + p);
                    hp[0] = lo;
                    hp[1] = hi;
                }
            }
        }
    }
}

// ---------------- fused cell GEMM + LSTM gates (transposed, gate-packed) ----------------
// C'[p][node], p = jcol*4+gate, K=256 (ax | ah). Lane reg r = gate r of jcol.
// Full K=256 B-panel staged once (80 KB LDS, ONE barrier); p-blocks looped in-kernel.

__global__ __launch_bounds__(TPB) void k_cell_t(
        const __hip_bfloat16* __restrict__ Ap,     // packed [8][32][64][8] for this step
        const __hip_bfloat16* __restrict__ axb, const __hip_bfloat16* __restrict__ ahb,
        const float* __restrict__ bias,            // bcell + s*512
        float* __restrict__ cbuf, float* __restrict__ hout,
        __half* __restrict__ houth,                // fp16 copy of h for next aggregate
        float* __restrict__ hfin, int N) {
    __shared__ __align__(16) short Bs[8][128 * 40];   // 8 K-chunks x (128 nodes x 32 bf16, stride 40)
    int tid = threadIdx.x;
    int wave = tid >> 6, lane = tid & 63;
    int w_p = wave >> 1, w_n = wave & 1;
    int n0 = blockIdx.x * 128;
    int quad = lane >> 4, m16 = lane & 15;
    f32x4 zero = {0.f, 0.f, 0.f, 0.f};

    // stage entire 128-node x 256-K panel, one barrier
    #pragma unroll
    for (int it = 0; it < 16; ++it) {
        int ks = it >> 1;
        int lin = ((it & 1) << 8) + tid;           // 0..511
        int row = lin >> 2, seg = lin & 3;
        const __hip_bfloat16* fsrc = (ks < 4) ? axb : ahb;
        int node = n0 + row;
        f32x4 v = zero;
        if (node < N) v = *(const f32x4*)(fsrc + (size_t)node * 128 + (ks & 3) * 32 + seg * 8);
        *(f32x4*)&Bs[ks][row * 40 + seg * 8] = v;
    }
    __syncthreads();

    for (int p0i = 0; p0i < 4; ++p0i) {
        f32x4 acc[4][4];
        #pragma unroll
        for (int t = 0; t < 4; ++t)
            #pragma unroll
            for (int g = 0; g < 4; ++g) acc[t][g] = zero;

        #pragma unroll
        for (int ks = 0; ks < 8; ++ks) {
            bf16x8 a[4], b[4];
            #pragma unroll
            for (int t = 0; t < 4; ++t)
                a[t] = *(const bf16x8*)(Ap + (((size_t)ks * 32 + p0i * 8 + w_p * 4 + t) * 64 + lane) * 8);
            #pragma unroll
            for (int g = 0; g < 4; ++g)
                b[g] = *(const bf16x8*)&Bs[ks][(w_n * 64 + g * 16 + m16) * 40 + quad * 8];
            #pragma unroll
            for (int t = 0; t < 4; ++t)
                #pragma unroll
                for (int g = 0; g < 4; ++g)
                    acc[t][g] = __builtin_amdgcn_mfma_f32_16x16x32_bf16(a[t], b[g], acc[t][g], 0, 0, 0);
        }

        #pragma unroll
        for (int t = 0; t < 4; ++t) {
            int p = p0i * 128 + w_p * 64 + t * 16 + quad * 4;
            int jcol = p >> 2;
            float bf = bias[jcol], bi = bias[128 + jcol], bo = bias[256 + jcol], bg = bias[384 + jcol];
            #pragma unroll
            for (int g = 0; g < 4; ++g) {
                int nd = n0 + w_n * 64 + g * 16 + m16;
                if (nd < N) {
                    float fv = sigf(acc[t][g].x + bf);
                    float iv = sigf(acc[t][g].y + bi);
                    float ov = sigf(acc[t][g].z + bo);
                    float gv = tanhfast(acc[t][g].w + bg);
                    size_t idx = (size_t)nd * 128 + jcol;
                    float cp = cbuf[idx];
                    float cn = fmaf(fv, cp, iv * gv);
                    cbuf[idx] = cn;
                    float hn = ov * tanhfast(cn);
                    hout[idx] = hn;
                    houth[idx] = __float2half(hn);
                    if (hfin) hfin[idx] = hn;
                }
            }
        }
    }
}

// ---------------- launch ----------------

extern "C" void kernel_launch(void* const* d_in, const int* in_sizes, int n_in,
                              void* d_out, int out_size, void* d_ws, size_t ws_size,
                              hipStream_t stream) {
    const float* x  = (const float*)d_in[0];
    const float* c  = (const float*)d_in[1];
    const int*   ei = (const int*)d_in[2];
    const float* Wh = (const float*)d_in[3];
    const float* bh = (const float*)d_in[4];
    const float* Wc = (const float*)d_in[5];
    const float* bc = (const float*)d_in[6];
    const float* Wcell = (const float*)d_in[7];
    const float* bcell = (const float*)d_in[8];
    float* out = (float*)d_out;

    const int N = in_sizes[0] / 128;
    const int E = in_sizes[2] / 2;
    const int S = in_sizes[7] / (256 * 512);
    const int* srcp = ei;
    const int* dstp = ei + E;

    // output layout: hs [S,N,128] | h_fin [N,128] | c_fin [N,128]
    float* hs   = out;
    float* hfin = out + (size_t)S * N * 128;
    float* cbuf = hfin + (size_t)N * 128;

    char* w = (char*)d_ws;
    size_t off = 0;
    auto alloc = [&](size_t bytes) -> void* {
        void* p = w + off;
        off += (bytes + 255) & ~(size_t)255;
        return p;
    };
    int*   counts  = (int*)alloc((size_t)N * 4);
    int*   offsets = (int*)alloc((size_t)(N + 1) * 4);
    int*   cursor  = (int*)alloc((size_t)N * 4);
    int*   sums    = (int*)alloc(256 * 4);
    int2*  csr_sw  = (int2*)alloc((size_t)E * 8);
    float* dinv    = (float*)alloc((size_t)N * 4);
    __hip_bfloat16* axb = (__hip_bfloat16*)alloc((size_t)N * 128 * 2);
    __hip_bfloat16* acb = (__hip_bfloat16*)alloc((size_t)N * 128 * 2);  // ac, then ah per step
    __half* xh = (__half*)alloc((size_t)N * 128 * 2);
    __half* ch = (__half*)alloc((size_t)N * 128 * 2);
    __half* hh = (__half*)alloc((size_t)N * 128 * 2);   // fp16 h (h0, then h_s)
    __hip_bfloat16* WhP = (__hip_bfloat16*)alloc(16384 * 2);
    __hip_bfloat16* WcP = (__hip_bfloat16*)alloc(16384 * 2);
    __hip_bfloat16* WcellP = (__hip_bfloat16*)alloc((size_t)S * 131072 * 2);
    (void)ws_size; (void)n_in; (void)out_size;

    hipMemsetAsync(counts, 0, (size_t)N * 4, stream);
    int eblk = (E + TPB - 1) / TPB;
    int nb   = (N + TPB - 1) / TPB;
    k_hist<<<eblk, TPB, 0, stream>>>(dstp, counts, E);
    k_scan_block<<<nb, TPB, 0, stream>>>(counts, offsets, sums, N);
    k_scan_tops<<<1, TPB, 0, stream>>>(sums, nb);
    k_scan_finish<<<nb, TPB, 0, stream>>>(counts, offsets, sums, cursor, dinv, N, E);
    k_csr_scatter<<<eblk, TPB, 0, stream>>>(srcp, dstp, dinv, cursor, csr_sw, E);

    // pack weights to MFMA frag order (bf16)
    k_pack_w128<<<64, TPB, 0, stream>>>(Wh, WhP);
    k_pack_w128<<<64, TPB, 0, stream>>>(Wc, WcP);
    k_pack_wcell<<<(S * 131072 + TPB - 1) / TPB, TPB, 0, stream>>>(Wcell, WcellP, S);

    // fp16 gather sources for x and c
    int n4 = N * 128 / 4;
    int cb = (n4 + TPB - 1) / TPB;
    k_f32tof16<<<cb, TPB, 0, stream>>>(x, xh, n4);
    k_f32tof16<<<cb, TPB, 0, stream>>>(c, ch, n4);

    int nagg = (N + 3) / 4;
    int ngt  = (N + 127) / 128;
    k_aggregate_h2<<<nagg, TPB, 0, stream>>>(xh, ch, axb, acb, offsets, csr_sw, dinv, N);
    k_gemm_t<<<ngt, TPB, 0, stream>>>(WhP, axb, bh, nullptr, hh, N);   // h0 only needed as fp16 gather src
    k_gemm_t<<<ngt, TPB, 0, stream>>>(WcP, acb, bc, cbuf, nullptr, N);

    for (int s = 0; s < S; ++s) {
        k_aggregate_h<<<nagg, TPB, 0, stream>>>(hh, acb, offsets, csr_sw, dinv, N);
        k_cell_t<<<ngt, TPB, 0, stream>>>(
            WcellP + (size_t)s * 131072, axb, acb, bcell + (size_t)s * 512,
            cbuf, hs + (size_t)s * N * 128, hh, (s == S - 1) ? hfin : nullptr, N);
    }
}

// Round 3
// 1328.949 us; speedup vs baseline: 1.2379x; 1.0131x over previous
//
#include <hip/hip_runtime.h>
#include <hip/hip_bf16.h>
#include <hip/hip_fp16.h>
#include <cstddef>

// GCN-LSTM decoder, N=50000, E=600000, H=O=128, S=8.
// GCN(feat,W,b) = (A_norm@feat)@W + b  (aggregate first, then GEMM).
// combined=[x,h] => A@combined = [A@x, A@h]; A@x precomputed once.
// GEMMs in bf16 MFMA (16x16x32), computed TRANSPOSED: C'[p][node]; cell GEMM
// gate-packed (p = jcol*4+gate) -> fused LSTM epilogue, no cross-lane traffic.
// Gather sources in fp16. Aggregate: lane (g,t)=(lane>>4,lane&15) gathers 16B
// (8 channels) of edge k+g -> ONE dwordx4 per wave covers 4 edges (1KB in
// flight/instr), metadata 8B broadcast per 16-lane group, shfl_xor reduce.
// Cell GEMM: full 256-K B-panel staged once in 80KB LDS (1 barrier), p-blocks
// looped in-kernel.

#define TPB 256

typedef __attribute__((ext_vector_type(8))) short bf16x8;   // 8 bf16 = 4 VGPR
typedef __attribute__((ext_vector_type(4))) float f32x4;

__device__ __forceinline__ float sigf(float x) {
    return 1.0f / (1.0f + __expf(-x));
}
__device__ __forceinline__ float tanhfast(float x) {
    return 1.0f - 2.0f / (__expf(2.0f * x) + 1.0f);
}

// ---------------- CSR build ----------------

__global__ void k_hist(const int* __restrict__ dst, int* __restrict__ counts, int E) {
    int e = blockIdx.x * TPB + threadIdx.x;
    if (e < E) atomicAdd(&counts[dst[e]], 1);
}

__global__ void k_scan_block(const int* __restrict__ counts, int* __restrict__ offsets,
                             int* __restrict__ sums, int N) {
    __shared__ int s[TPB];
    int tid = threadIdx.x;
    int gid = blockIdx.x * TPB + tid;
    int v = (gid < N) ? counts[gid] : 0;
    s[tid] = v;
    __syncthreads();
    for (int d = 1; d < TPB; d <<= 1) {
        int t = (tid >= d) ? s[tid - d] : 0;
        __syncthreads();
        s[tid] += t;
        __syncthreads();
    }
    if (gid < N) offsets[gid] = s[tid] - v;
    if (tid == TPB - 1) sums[blockIdx.x] = s[tid];
}

__global__ void k_scan_tops(int* __restrict__ sums, int nb) {
    __shared__ int s[TPB];
    int tid = threadIdx.x;
    int v = (tid < nb) ? sums[tid] : 0;
    s[tid] = v;
    __syncthreads();
    for (int d = 1; d < TPB; d <<= 1) {
        int t = (tid >= d) ? s[tid - d] : 0;
        __syncthreads();
        s[tid] += t;
        __syncthreads();
    }
    if (tid < nb) sums[tid] = s[tid] - v;
}

__global__ void k_scan_finish(const int* __restrict__ counts, int* __restrict__ offsets,
                              const int* __restrict__ sums, int* __restrict__ cursor,
                              float* __restrict__ dinv, int N, int E) {
    int gid = blockIdx.x * TPB + threadIdx.x;
    if (gid < N) {
        int off = offsets[gid] + sums[blockIdx.x];
        offsets[gid] = off;
        cursor[gid]  = off;
        dinv[gid]    = rsqrtf((float)(counts[gid] + 1));
    }
    if (gid == 0) offsets[N] = E;
}

__global__ void k_csr_scatter(const int* __restrict__ src, const int* __restrict__ dst,
                              const float* __restrict__ dinv, int* __restrict__ cursor,
                              int2* __restrict__ csr_sw, int E) {
    int e = blockIdx.x * TPB + threadIdx.x;
    if (e >= E) return;
    int d = dst[e], s = src[e];
    int pos = atomicAdd(&cursor[d], 1);
    int2 r;
    r.x = s;
    r.y = __float_as_int(dinv[s] * dinv[d]);
    csr_sw[pos] = r;
}

// ---------------- fp32 -> fp16 convert ----------------

__global__ void k_f32tof16(const float* __restrict__ in, __half* __restrict__ out, int n4) {
    int i = blockIdx.x * TPB + threadIdx.x;    // 4 floats per thread
    if (i >= n4) return;
    float4 v = ((const float4*)in)[i];
    __half2 lo = __floats2half2_rn(v.x, v.y);
    __half2 hi = __floats2half2_rn(v.z, v.w);
    ((__half2*)out)[2 * i]     = lo;
    ((__half2*)out)[2 * i + 1] = hi;
}

// ---------------- aggregation: agg(bf16) = A_norm @ feat(fp16) ----------------
// One wave per node. Lane (g,t): g=lane>>4 edge slot, t=lane&15 channel block.
// Per iteration: one dwordx4 gather covers 4 edges (8 channels/lane).

union HU { f32x4 v; __half2 h[4]; };

__global__ __launch_bounds__(TPB) void k_aggregate_h(
        const __half* __restrict__ feat, __hip_bfloat16* __restrict__ agg,
        const int* __restrict__ offsets, const int2* __restrict__ sw,
        const float* __restrict__ dinv, int N) {
    int node = blockIdx.x * 4 + (threadIdx.x >> 6);
    if (node >= N) return;
    int lane = threadIdx.x & 63;
    int g = lane >> 4, t = lane & 15;
    const f32x4* f4 = (const f32x4*)feat;      // row = 16 units of 16B
    float acc[8];
    #pragma unroll
    for (int j = 0; j < 8; ++j) acc[j] = 0.f;

    int b = offsets[node], e = offsets[node + 1];
    for (int k = b; k < e; k += 4) {
        int kk = k + g;
        int kkc = (kk < e) ? kk : (e - 1);
        int2 sv = sw[kkc];
        float w = (kk < e) ? __int_as_float(sv.y) : 0.f;
        HU u;
        u.v = f4[(size_t)sv.x * 16 + t];
        #pragma unroll
        for (int j = 0; j < 4; ++j) {
            float2 vv = __half22float2(u.h[j]);
            acc[2 * j]     = fmaf(w, vv.x, acc[2 * j]);
            acc[2 * j + 1] = fmaf(w, vv.y, acc[2 * j + 1]);
        }
    }
    // sum the 4 edge groups
    #pragma unroll
    for (int j = 0; j < 8; ++j) {
        acc[j] += __shfl_xor(acc[j], 16);
        acc[j] += __shfl_xor(acc[j], 32);
    }
    if (g == 0) {
        float di = dinv[node];
        float w0 = di * di;
        HU u;
        u.v = f4[(size_t)node * 16 + t];
        union { f32x4 v; __hip_bfloat162 b2[4]; } o;
        #pragma unroll
        for (int j = 0; j < 4; ++j) {
            float2 vv = __half22float2(u.h[j]);
            float ox = fmaf(w0, vv.x, acc[2 * j]);
            float oy = fmaf(w0, vv.y, acc[2 * j + 1]);
            o.b2[j].x = __float2bfloat16(ox);
            o.b2[j].y = __float2bfloat16(oy);
        }
        *(f32x4*)(agg + (size_t)node * 128 + t * 8) = o.v;
    }
}

// dual-source aggregate (x and c share the CSR stream)
__global__ __launch_bounds__(TPB) void k_aggregate_h2(
        const __half* __restrict__ fa, const __half* __restrict__ fb,
        __hip_bfloat16* __restrict__ aggA, __hip_bfloat16* __restrict__ aggB,
        const int* __restrict__ offsets, const int2* __restrict__ sw,
        const float* __restrict__ dinv, int N) {
    int node = blockIdx.x * 4 + (threadIdx.x >> 6);
    if (node >= N) return;
    int lane = threadIdx.x & 63;
    int g = lane >> 4, t = lane & 15;
    const f32x4* fa4 = (const f32x4*)fa;
    const f32x4* fb4 = (const f32x4*)fb;
    float accA[8], accB[8];
    #pragma unroll
    for (int j = 0; j < 8; ++j) { accA[j] = 0.f; accB[j] = 0.f; }

    int b = offsets[node], e = offsets[node + 1];
    for (int k = b; k < e; k += 4) {
        int kk = k + g;
        int kkc = (kk < e) ? kk : (e - 1);
        int2 sv = sw[kkc];
        float w = (kk < e) ? __int_as_float(sv.y) : 0.f;
        size_t ri = (size_t)sv.x * 16 + t;
        HU ua, ub;
        ua.v = fa4[ri];
        ub.v = fb4[ri];
        #pragma unroll
        for (int j = 0; j < 4; ++j) {
            float2 va = __half22float2(ua.h[j]);
            float2 vb = __half22float2(ub.h[j]);
            accA[2 * j]     = fmaf(w, va.x, accA[2 * j]);
            accA[2 * j + 1] = fmaf(w, va.y, accA[2 * j + 1]);
            accB[2 * j]     = fmaf(w, vb.x, accB[2 * j]);
            accB[2 * j + 1] = fmaf(w, vb.y, accB[2 * j + 1]);
        }
    }
    #pragma unroll
    for (int j = 0; j < 8; ++j) {
        accA[j] += __shfl_xor(accA[j], 16);
        accA[j] += __shfl_xor(accA[j], 32);
        accB[j] += __shfl_xor(accB[j], 16);
        accB[j] += __shfl_xor(accB[j], 32);
    }
    if (g == 0) {
        float di = dinv[node];
        float w0 = di * di;
        size_t ri = (size_t)node * 16 + t;
        HU ua, ub;
        ua.v = fa4[ri];
        ub.v = fb4[ri];
        union { f32x4 v; __hip_bfloat162 b2[4]; } oa, ob;
        #pragma unroll
        for (int j = 0; j < 4; ++j) {
            float2 va = __half22float2(ua.h[j]);
            float2 vb = __half22float2(ub.h[j]);
            oa.b2[j].x = __float2bfloat16(fmaf(w0, va.x, accA[2 * j]));
            oa.b2[j].y = __float2bfloat16(fmaf(w0, va.y, accA[2 * j + 1]));
            ob.b2[j].x = __float2bfloat16(fmaf(w0, vb.x, accB[2 * j]));
            ob.b2[j].y = __float2bfloat16(fmaf(w0, vb.y, accB[2 * j + 1]));
        }
        *(f32x4*)(aggA + (size_t)node * 128 + t * 8) = oa.v;
        *(f32x4*)(aggB + (size_t)node * 128 + t * 8) = ob.v;
    }
}

// ---------------- weight packing into MFMA A-frag order ----------------
// Layout: Wp[ks][pblk][lane][j] = W'[pblk*16 + (lane&15)][ks*32 + (lane>>4)*8 + j]

__global__ void k_pack_w128(const float* __restrict__ W, __hip_bfloat16* __restrict__ Wp) {
    int idx = blockIdx.x * TPB + threadIdx.x;     // 4*8*64*8 = 16384
    if (idx >= 16384) return;
    int j = idx & 7, lane = (idx >> 3) & 63, pblk = (idx >> 9) & 7, ks = idx >> 12;
    int k = ks * 32 + (lane >> 4) * 8 + j;
    int col = pblk * 16 + (lane & 15);
    Wp[idx] = __float2bfloat16(W[k * 128 + col]);
}

// cell weights: p = jcol*4 + gate  (gate order f,i,o,g matches bcell blocks)
__global__ void k_pack_wcell(const float* __restrict__ W, __hip_bfloat16* __restrict__ Wp, int S) {
    int idx = blockIdx.x * TPB + threadIdx.x;     // S * 8*32*64*8 = S*131072
    if (idx >= S * 131072) return;
    int j = idx & 7, lane = (idx >> 3) & 63, pblk = (idx >> 9) & 31;
    int ks = (idx >> 14) & 7, s = idx >> 17;
    int p = pblk * 16 + (lane & 15);
    int jcol = p >> 2, gate = p & 3;
    int k = ks * 32 + (lane >> 4) * 8 + j;
    Wp[idx] = __float2bfloat16(W[(size_t)s * 131072 + k * 512 + gate * 128 + jcol]);
}

// ---------------- transposed MFMA GEMM: C[node][128] = agg @ W + b ----------------
// M = 128 weight cols (p), N-dim = nodes. Block: 128p x 128nodes, 4 waves 2x2.
// Cout (fp32) and outh (fp16) independently nullable.

__global__ __launch_bounds__(TPB) void k_gemm_t(
        const __hip_bfloat16* __restrict__ Ap,     // packed [4][8][64][8]
        const __hip_bfloat16* __restrict__ featb,  // [N][128] bf16
        const float* __restrict__ bias, float* __restrict__ Cout,
        __half* __restrict__ outh, int N) {
    __shared__ __align__(16) short Bs[128 * 40];   // 128 nodes x 32 bf16, stride 40
    int tid = threadIdx.x;
    int wave = tid >> 6, lane = tid & 63;
    int w_p = wave >> 1, w_n = wave & 1;
    int n0 = blockIdx.x * 128;
    int quad = lane >> 4, m16 = lane & 15;
    f32x4 zero = {0.f, 0.f, 0.f, 0.f};
    f32x4 acc[4][4];
    #pragma unroll
    for (int t = 0; t < 4; ++t)
        #pragma unroll
        for (int g = 0; g < 4; ++g) acc[t][g] = zero;

    for (int ks = 0; ks < 4; ++ks) {
        int kbase = ks * 32;
        __syncthreads();
        #pragma unroll
        for (int it = 0; it < 2; ++it) {
            int lin = it * TPB + tid;
            int row = lin >> 2, seg = lin & 3;
            int node = n0 + row;
            f32x4 v = zero;
            if (node < N) v = *(const f32x4*)(featb + (size_t)node * 128 + kbase + seg * 8);
            *(f32x4*)&Bs[row * 40 + seg * 8] = v;
        }
        __syncthreads();
        bf16x8 a[4], b[4];
        #pragma unroll
        for (int t = 0; t < 4; ++t)
            a[t] = *(const bf16x8*)(Ap + (((size_t)ks * 8 + w_p * 4 + t) * 64 + lane) * 8);
        #pragma unroll
        for (int g = 0; g < 4; ++g)
            b[g] = *(const bf16x8*)&Bs[(w_n * 64 + g * 16 + m16) * 40 + quad * 8];
        #pragma unroll
        for (int t = 0; t < 4; ++t)
            #pragma unroll
            for (int g = 0; g < 4; ++g)
                acc[t][g] = __builtin_amdgcn_mfma_f32_16x16x32_bf16(a[t], b[g], acc[t][g], 0, 0, 0);
    }
    #pragma unroll
    for (int t = 0; t < 4; ++t) {
        int p = w_p * 64 + t * 16 + quad * 4;
        f32x4 bv = *(const f32x4*)(bias + p);
        #pragma unroll
        for (int g = 0; g < 4; ++g) {
            int nd = n0 + w_n * 64 + g * 16 + m16;
            if (nd < N) {
                f32x4 o = acc[t][g] + bv;
                if (Cout) *(f32x4*)(Cout + (size_t)nd * 128 + p) = o;
                if (outh) {
                    __half2 lo = __floats2half2_rn(o.x, o.y);
                    __half2 hi = __floats2half2_rn(o.z, o.w);
                    __half2* hp = (__half2*)(outh + (size_t)nd * 128 + p);
                    hp[0] = lo;
                    hp[1] = hi;
                }
            }
        }
    }
}

// ---------------- fused cell GEMM + LSTM gates (transposed, gate-packed) ----------------
// C'[p][node], p = jcol*4+gate, K=256 (ax | ah). Lane reg r = gate r of jcol.
// Full K=256 B-panel staged once (80 KB LDS, ONE barrier); p-blocks looped in-kernel.

__global__ __launch_bounds__(TPB) void k_cell_t(
        const __hip_bfloat16* __restrict__ Ap,     // packed [8][32][64][8] for this step
        const __hip_bfloat16* __restrict__ axb, const __hip_bfloat16* __restrict__ ahb,
        const float* __restrict__ bias,            // bcell + s*512
        float* __restrict__ cbuf, float* __restrict__ hout,
        __half* __restrict__ houth,                // fp16 copy of h for next aggregate
        float* __restrict__ hfin, int N) {
    __shared__ __align__(16) short Bs[8][128 * 40];   // 8 K-chunks x (128 nodes x 32 bf16, stride 40)
    int tid = threadIdx.x;
    int wave = tid >> 6, lane = tid & 63;
    int w_p = wave >> 1, w_n = wave & 1;
    int n0 = blockIdx.x * 128;
    int quad = lane >> 4, m16 = lane & 15;
    f32x4 zero = {0.f, 0.f, 0.f, 0.f};

    // stage entire 128-node x 256-K panel, one barrier
    #pragma unroll
    for (int it = 0; it < 16; ++it) {
        int ks = it >> 1;
        int lin = ((it & 1) << 8) + tid;           // 0..511
        int row = lin >> 2, seg = lin & 3;
        const __hip_bfloat16* fsrc = (ks < 4) ? axb : ahb;
        int node = n0 + row;
        f32x4 v = zero;
        if (node < N) v = *(const f32x4*)(fsrc + (size_t)node * 128 + (ks & 3) * 32 + seg * 8);
        *(f32x4*)&Bs[ks][row * 40 + seg * 8] = v;
    }
    __syncthreads();

    for (int p0i = 0; p0i < 4; ++p0i) {
        f32x4 acc[4][4];
        #pragma unroll
        for (int t = 0; t < 4; ++t)
            #pragma unroll
            for (int g = 0; g < 4; ++g) acc[t][g] = zero;

        #pragma unroll
        for (int ks = 0; ks < 8; ++ks) {
            bf16x8 a[4], b[4];
            #pragma unroll
            for (int t = 0; t < 4; ++t)
                a[t] = *(const bf16x8*)(Ap + (((size_t)ks * 32 + p0i * 8 + w_p * 4 + t) * 64 + lane) * 8);
            #pragma unroll
            for (int g = 0; g < 4; ++g)
                b[g] = *(const bf16x8*)&Bs[ks][(w_n * 64 + g * 16 + m16) * 40 + quad * 8];
            #pragma unroll
            for (int t = 0; t < 4; ++t)
                #pragma unroll
                for (int g = 0; g < 4; ++g)
                    acc[t][g] = __builtin_amdgcn_mfma_f32_16x16x32_bf16(a[t], b[g], acc[t][g], 0, 0, 0);
        }

        #pragma unroll
        for (int t = 0; t < 4; ++t) {
            int p = p0i * 128 + w_p * 64 + t * 16 + quad * 4;
            int jcol = p >> 2;
            float bf = bias[jcol], bi = bias[128 + jcol], bo = bias[256 + jcol], bg = bias[384 + jcol];
            #pragma unroll
            for (int g = 0; g < 4; ++g) {
                int nd = n0 + w_n * 64 + g * 16 + m16;
                if (nd < N) {
                    float fv = sigf(acc[t][g].x + bf);
                    float iv = sigf(acc[t][g].y + bi);
                    float ov = sigf(acc[t][g].z + bo);
                    float gv = tanhfast(acc[t][g].w + bg);
                    size_t idx = (size_t)nd * 128 + jcol;
                    float cp = cbuf[idx];
                    float cn = fmaf(fv, cp, iv * gv);
                    cbuf[idx] = cn;
                    float hn = ov * tanhfast(cn);
                    hout[idx] = hn;
                    houth[idx] = __float2half(hn);
                    if (hfin) hfin[idx] = hn;
                }
            }
        }
    }
}

// ---------------- launch ----------------

extern "C" void kernel_launch(void* const* d_in, const int* in_sizes, int n_in,
                              void* d_out, int out_size, void* d_ws, size_t ws_size,
                              hipStream_t stream) {
    const float* x  = (const float*)d_in[0];
    const float* c  = (const float*)d_in[1];
    const int*   ei = (const int*)d_in[2];
    const float* Wh = (const float*)d_in[3];
    const float* bh = (const float*)d_in[4];
    const float* Wc = (const float*)d_in[5];
    const float* bc = (const float*)d_in[6];
    const float* Wcell = (const float*)d_in[7];
    const float* bcell = (const float*)d_in[8];
    float* out = (float*)d_out;

    const int N = in_sizes[0] / 128;
    const int E = in_sizes[2] / 2;
    const int S = in_sizes[7] / (256 * 512);
    const int* srcp = ei;
    const int* dstp = ei + E;

    // output layout: hs [S,N,128] | h_fin [N,128] | c_fin [N,128]
    float* hs   = out;
    float* hfin = out + (size_t)S * N * 128;
    float* cbuf = hfin + (size_t)N * 128;

    char* w = (char*)d_ws;
    size_t off = 0;
    auto alloc = [&](size_t bytes) -> void* {
        void* p = w + off;
        off += (bytes + 255) & ~(size_t)255;
        return p;
    };
    int*   counts  = (int*)alloc((size_t)N * 4);
    int*   offsets = (int*)alloc((size_t)(N + 1) * 4);
    int*   cursor  = (int*)alloc((size_t)N * 4);
    int*   sums    = (int*)alloc(256 * 4);
    int2*  csr_sw  = (int2*)alloc((size_t)E * 8);
    float* dinv    = (float*)alloc((size_t)N * 4);
    __hip_bfloat16* axb = (__hip_bfloat16*)alloc((size_t)N * 128 * 2);
    __hip_bfloat16* acb = (__hip_bfloat16*)alloc((size_t)N * 128 * 2);  // ac, then ah per step
    __half* xh = (__half*)alloc((size_t)N * 128 * 2);
    __half* ch = (__half*)alloc((size_t)N * 128 * 2);
    __half* hh = (__half*)alloc((size_t)N * 128 * 2);   // fp16 h (h0, then h_s)
    __hip_bfloat16* WhP = (__hip_bfloat16*)alloc(16384 * 2);
    __hip_bfloat16* WcP = (__hip_bfloat16*)alloc(16384 * 2);
    __hip_bfloat16* WcellP = (__hip_bfloat16*)alloc((size_t)S * 131072 * 2);
    (void)ws_size; (void)n_in; (void)out_size;

    hipMemsetAsync(counts, 0, (size_t)N * 4, stream);
    int eblk = (E + TPB - 1) / TPB;
    int nb   = (N + TPB - 1) / TPB;
    k_hist<<<eblk, TPB, 0, stream>>>(dstp, counts, E);
    k_scan_block<<<nb, TPB, 0, stream>>>(counts, offsets, sums, N);
    k_scan_tops<<<1, TPB, 0, stream>>>(sums, nb);
    k_scan_finish<<<nb, TPB, 0, stream>>>(counts, offsets, sums, cursor, dinv, N, E);
    k_csr_scatter<<<eblk, TPB, 0, stream>>>(srcp, dstp, dinv, cursor, csr_sw, E);

    // pack weights to MFMA frag order (bf16)
    k_pack_w128<<<64, TPB, 0, stream>>>(Wh, WhP);
    k_pack_w128<<<64, TPB, 0, stream>>>(Wc, WcP);
    k_pack_wcell<<<(S * 131072 + TPB - 1) / TPB, TPB, 0, stream>>>(Wcell, WcellP, S);

    // fp16 gather sources for x and c
    int n4 = N * 128 / 4;
    int cb = (n4 + TPB - 1) / TPB;
    k_f32tof16<<<cb, TPB, 0, stream>>>(x, xh, n4);
    k_f32tof16<<<cb, TPB, 0, stream>>>(c, ch, n4);

    int nagg = (N + 3) / 4;
    int ngt  = (N + 127) / 128;
    k_aggregate_h2<<<nagg, TPB, 0, stream>>>(xh, ch, axb, acb, offsets, csr_sw, dinv, N);
    k_gemm_t<<<ngt, TPB, 0, stream>>>(WhP, axb, bh, nullptr, hh, N);   // h0 only needed as fp16 gather src
    k_gemm_t<<<ngt, TPB, 0, stream>>>(WcP, acb, bc, cbuf, nullptr, N);

    for (int s = 0; s < S; ++s) {
        k_aggregate_h<<<nagg, TPB, 0, stream>>>(hh, acb, offsets, csr_sw, dinv, N);
        k_cell_t<<<ngt, TPB, 0, stream>>>(
            WcellP + (size_t)s * 131072, axb, acb, bcell + (size_t)s * 512,
            cbuf, hs + (size_t)s * N * 128, hh, (s == S - 1) ? hfin : nullptr, N);
    }
}